// Round 9
// baseline (697.433 us; speedup 1.0000x reference)
//
#include <hip/hip_runtime.h>
#include <hip/hip_bf16.h>
#include <stdint.h>

// Problem constants
#define MM   32768   // B*S
#define FFD  1024    // F
#define NQKV 3072    // 3*F

typedef __bf16 bf16x8 __attribute__((ext_vector_type(8)));
typedef float  f32x4  __attribute__((ext_vector_type(4)));

__device__ __forceinline__ unsigned short f2bf_bits(float f){
  __hip_bfloat16 h = __float2bfloat16(f);
  unsigned short u;
  __builtin_memcpy(&u, &h, 2);
  return u;
}

__device__ __forceinline__ void gld16(const void* g, void* l){
  const unsigned int* gu = (const unsigned int*)g;
  unsigned int* lu = (unsigned int*)l;
  __builtin_amdgcn_global_load_lds(
      (const __attribute__((address_space(1))) unsigned int*)gu,
      (__attribute__((address_space(3))) unsigned int*)lu,
      16, 0, 0);
}

// Raw barrier (no vmcnt(0) auto-drain like __syncthreads) + compiler memory fence
#define BARRIER() do { asm volatile("" ::: "memory"); \
                       __builtin_amdgcn_s_barrier();  \
                       asm volatile("" ::: "memory"); } while(0)

// ---------- convert fp32 -> bf16, 4 elems/thread ----------
__global__ __launch_bounds__(256) void k_convert_bf16(const float* __restrict__ in,
                                                      unsigned short* __restrict__ out,
                                                      int n4){
  int i = blockIdx.x * 256 + threadIdx.x;
  if (i >= n4) return;
  float4 v = ((const float4*)in)[i];
  ushort4 r;
  r.x = f2bf_bits(v.x); r.y = f2bf_bits(v.y);
  r.z = f2bf_bits(v.z); r.w = f2bf_bits(v.w);
  ((ushort4*)out)[i] = r;
}

// ---------- all 4 weight transposes in one launch (z picks matrix) ----------
__global__ __launch_bounds__(256) void k_transpose4(const float* __restrict__ Wq,
                                                    const float* __restrict__ Wk,
                                                    const float* __restrict__ Wv,
                                                    const float* __restrict__ Wo,
                                                    unsigned short* __restrict__ Wqkv_t,
                                                    unsigned short* __restrict__ Wo_t){
  __shared__ float tile[32][33];
  const float* in;
  unsigned short* out;
  switch (blockIdx.z){
    case 0:  in = Wq; out = Wqkv_t;               break;
    case 1:  in = Wk; out = Wqkv_t + 1024 * 1024; break;
    case 2:  in = Wv; out = Wqkv_t + 2048 * 1024; break;
    default: in = Wo; out = Wo_t;                 break;
  }
  int bc = blockIdx.x * 32, br = blockIdx.y * 32;
  int tx = threadIdx.x & 31, ty = threadIdx.x >> 5;
  #pragma unroll
  for (int j = 0; j < 32; j += 8)
    tile[ty + j][tx] = in[(size_t)(br + ty + j) * 1024 + bc + tx];
  __syncthreads();
  #pragma unroll
  for (int j = 0; j < 32; j += 8)
    out[(size_t)(bc + ty + j) * 1024 + br + tx] = f2bf_bits(tile[tx][ty + j]);
}

// ---------- GEMM1: C(MxN) = A(MxK)*Bt(NxK)^T + bias -> bf16 ----------
// r2-verified structure (best measured: ~228us, 0 conflicts, 189MB fetch):
// 256x256 tile, BK=32, 512 threads (8 waves 2Mx4N), ring-4 LDS staged 3 tiles
// ahead, ONE counted {s_waitcnt vmcnt(8); s_barrier} per K-tile, free-drift
// body, LDS-bounce bf16 epilogue (ideal WRITE_SIZE).
__global__ __launch_bounds__(512, 2) void k_gemm_bt(
    const unsigned short* __restrict__ A,
    const unsigned short* __restrict__ Bt,
    const float* __restrict__ b0, const float* __restrict__ b1, const float* __restrict__ b2,
    unsigned short* __restrict__ Cout, int M, int N, int K)
{
  __shared__ alignas(16) char smem[131072];

  const int tid  = threadIdx.x;
  const int lane = tid & 63;
  const int wave = tid >> 6;
  const int wr = wave >> 2, wc = wave & 3;       // 2 x 4 wave grid
  const int quad = lane >> 4, lrow = lane & 15;
  const int sa = ((lrow >> 1) & 3) << 4;         // read-side XOR swizzle bits

  // XCD-aware bijective block swizzle (grid multiple of 8)
  const int nwgx = gridDim.x;
  int nwg = nwgx * gridDim.y;
  int bid = blockIdx.y * nwgx + blockIdx.x;
  int cpx = nwg >> 3;
  int nid = (bid & 7) * cpx + (bid >> 3);
  int by = nid / nwgx;
  int bx = nid - by * nwgx;

  const long rowBase = (long)by * 256;
  const long colBase = (long)bx * 256;

  f32x4 acc[8][4];
  #pragma unroll
  for (int i = 0; i < 8; i++)
    #pragma unroll
    for (int j = 0; j < 4; j++)
      acc[i][j] = (f32x4){0.f, 0.f, 0.f, 0.f};

  const int swz8 = 8 * ((tid & 3) ^ ((tid >> 3) & 3));
  const unsigned short* gA = A  + (rowBase + (tid >> 2)) * (long)K + swz8;
  const unsigned short* gB = Bt + (colBase + (tid >> 2)) * (long)K + swz8;
  const long hstep = 128L * K;

  const int nk = K >> 5;

  #pragma unroll
  for (int tt = 0; tt < 3; ++tt){
    char* nb = smem + tt * 32768;
    gld16(gA + tt * 32,         nb +         tid * 16);
    gld16(gA + tt * 32 + hstep, nb +  8192 + tid * 16);
    gld16(gB + tt * 32,         nb + 16384 + tid * 16);
    gld16(gB + tt * 32 + hstep, nb + 24576 + tid * 16);
  }

  for (int t = 0; t < nk; ++t){
    if (t <= nk - 3)      asm volatile("s_waitcnt vmcnt(8)" ::: "memory");
    else if (t == nk - 2) asm volatile("s_waitcnt vmcnt(4)" ::: "memory");
    else                  asm volatile("s_waitcnt vmcnt(0)" ::: "memory");
    BARRIER();

    char* buf = smem + (t & 3) * 32768;
    if (t < nk - 3){
      char* nb = smem + ((t + 3) & 3) * 32768;
      const unsigned short* sA = gA + (long)(t + 3) * 32;
      const unsigned short* sB = gB + (long)(t + 3) * 32;
      gld16(sA,         nb +         tid * 16);
      gld16(sA + hstep, nb +  8192 + tid * 16);
      gld16(sB,         nb + 16384 + tid * 16);
      gld16(sB + hstep, nb + 24576 + tid * 16);
    }

    bf16x8 bfr[4];
    const char* bb = buf + 16384 + wc * 4096 + lrow * 64 + ((quad * 16) ^ sa);
    #pragma unroll
    for (int n = 0; n < 4; ++n)
      bfr[n] = *(const bf16x8*)(bb + n * 1024);

    #pragma unroll
    for (int p = 0; p < 2; ++p){
      bf16x8 af[4];
      const char* ab = buf + wr * 8192 + p * 4096 + lrow * 64 + ((quad * 16) ^ sa);
      #pragma unroll
      for (int f = 0; f < 4; ++f)
        af[f] = *(const bf16x8*)(ab + f * 1024);
      __builtin_amdgcn_s_setprio(1);
      #pragma unroll
      for (int f = 0; f < 4; ++f)
        #pragma unroll
        for (int n = 0; n < 4; ++n)
          acc[p * 4 + f][n] =
              __builtin_amdgcn_mfma_f32_16x16x32_bf16(af[f], bfr[n], acc[p * 4 + f][n], 0, 0, 0);
      __builtin_amdgcn_s_setprio(0);
    }
  }

  // epilogue: LDS-bounce -> coalesced 16B bf16 stores
  BARRIER();
  #pragma unroll
  for (int n = 0; n < 4; ++n){
    int lcol = wc * 64 + n * 16 + lrow;
    long col = colBase + lcol;
    const float* bp = (col < 1024) ? b0 : ((col < 2048) ? b1 : b2);
    float bias = bp[col & 1023];
    #pragma unroll
    for (int m = 0; m < 8; ++m){
      int row0 = wr * 128 + (m >> 2) * 64 + (m & 3) * 16 + quad * 4;
      int sw = ((row0 >> 2) & 3) << 5;
      #pragma unroll
      for (int r = 0; r < 4; ++r){
        float v = acc[m][n][r] + bias;
        int byte = (row0 + r) * 512 + ((lcol * 2) ^ sw);
        *(unsigned short*)(smem + byte) = f2bf_bits(v);
      }
    }
  }
  asm volatile("s_waitcnt lgkmcnt(0)" ::: "memory");
  BARRIER();
  #pragma unroll
  for (int i = 0; i < 16; ++i){
    int c = i * 512 + tid;
    int row = c >> 5, cidx = c & 31;
    int rb = (cidx ^ (((row >> 2) & 3) << 1)) * 16;
    uint4 u = *(const uint4*)(smem + row * 512 + rb);
    *(uint4*)(Cout + (rowBase + row) * (long)N + colBase + cidx * 8) = u;
  }
}

// ---------- fused GEMM2 + bias + LayerNorm -> fp32 out ----------
// Tile 64 rows x FULL 1024 cols, 512 threads (8 waves, each 64x128 cols),
// acc[4][8]. A (aout) staged in a 3x4KB LDS ring; staging gld16 issued AFTER
// the B fragment loads so the compiler's pre-MFMA B-wait is vmcnt(1) and the
// staging load stays in flight across the iteration (vmcnt is in-order).
// B (Wo^T, 2MB, L2-resident) read as fragments DIRECTLY from global.
// Each block owns complete rows -> LN stats from accumulators (lrow shfl
// reduce + 4KB cross-wave LDS reduce, no atomics); normalized fp32 written
// straight to d_out via a 4-pass LDS bounce (16 rows x 1024 cols per pass,
// 256 16B-chunks per row -> row = c>>8, cx = c&255  [r8 bug: >>6/&63 OOB]).
__global__ __launch_bounds__(512) void k_gemm2_ln(
    const unsigned short* __restrict__ A,
    const unsigned short* __restrict__ Bt,
    const float* __restrict__ bo,
    const float* __restrict__ gamma, const float* __restrict__ beta,
    float* __restrict__ out)
{
  __shared__ alignas(16) char smem[69632];   // [0,64K) bounce / [0,12K) A-ring; [64K,68K) stats

  const int tid  = threadIdx.x;
  const int lane = tid & 63;
  const int wave = tid >> 6;                 // wave covers cols wave*128..+128
  const int quad = lane >> 4, lrow = lane & 15;
  const int csw  = (quad ^ ((lrow >> 1) & 3)) << 4;   // r2-style swizzle (2-way max)

  // XCD swizzle (512 blocks, %8==0)
  int nwg = gridDim.x;
  int bid = blockIdx.x;
  int cpx = nwg >> 3;
  int nid = (bid & 7) * cpx + (bid >> 3);
  const long rowBase = (long)nid * 64;

  f32x4 acc[4][8];
  #pragma unroll
  for (int i = 0; i < 4; i++)
    #pragma unroll
    for (int j = 0; j < 8; j++)
      acc[i][j] = (f32x4){0.f, 0.f, 0.f, 0.f};

  // A staging: threads 0-255 cover (row = tid>>2 in [0,64), chunk tid&3),
  // global chunk pre-swizzled (tid&3)^((tid>>3)&3) so linear LDS + csw reads match.
  const int swz8 = 8 * ((tid & 3) ^ ((tid >> 3) & 3));
  const unsigned short* gA = A + (rowBase + (tid >> 2)) * 1024L + swz8;
  const int t16 = tid * 16;
  const int nk = 32;   // K=1024 / 32

  // prologue: tiles 0,1 -> slots 0,1 (1 gld16 per staging thread per tile)
  if (tid < 256){
    gld16(gA,      smem        + t16);
    gld16(gA + 32, smem + 4096 + t16);
  }

  for (int t = 0; t < nk; ++t){
    if (t < nk - 1) asm volatile("s_waitcnt vmcnt(1)" ::: "memory");
    else            asm volatile("s_waitcnt vmcnt(0)" ::: "memory");
    BARRIER();   // tile t landed; slot (t+2)%3 free (tile t-1's reads drained pre-MFMA)

    const char* buf = smem + (t % 3) * 4096;

    // B fragments direct from global (L2-resident Wo^T)
    bf16x8 bfr[8];
    #pragma unroll
    for (int n = 0; n < 8; ++n)
      bfr[n] = *(const bf16x8*)(Bt + (size_t)(wave * 128 + n * 16 + lrow) * 1024 + t * 32 + quad * 8);
    bf16x8 af[4];
    #pragma unroll
    for (int m = 0; m < 4; ++m)
      af[m] = *(const bf16x8*)(buf + (m * 16 + lrow) * 64 + csw);

    // stage tile t+2 AFTER the B loads (keeps gld16 newest -> B-wait = vmcnt(1))
    if (t < nk - 2 && tid < 256)
      gld16(gA + (long)(t + 2) * 32, smem + ((t + 2) % 3) * 4096 + t16);

    __builtin_amdgcn_s_setprio(1);
    #pragma unroll
    for (int m = 0; m < 4; ++m)
      #pragma unroll
      for (int n = 0; n < 8; ++n)
        acc[m][n] = __builtin_amdgcn_mfma_f32_16x16x32_bf16(af[m], bfr[n], acc[m][n], 0, 0, 0);
    __builtin_amdgcn_s_setprio(0);
  }

  // ---------------- fused bias + LN epilogue ----------------
  // C/D layout: col = lrow (per n-frag), row = m*16 + quad*4 + r.
  float gv[8], bv[8];
  #pragma unroll
  for (int n = 0; n < 8; ++n){
    int col = wave * 128 + n * 16 + lrow;
    float bias = bo[col];
    gv[n] = gamma[col]; bv[n] = beta[col];
    #pragma unroll
    for (int m = 0; m < 4; ++m)
      #pragma unroll
      for (int r = 0; r < 4; ++r)
        acc[m][n][r] += bias;
  }

  // per-row partial sums over this wave's 128 cols -> stats LDS
  float* stats = (float*)(smem + 65536);   // [wave][64 rows][2]
  #pragma unroll
  for (int m = 0; m < 4; ++m)
    #pragma unroll
    for (int r = 0; r < 4; ++r){
      float p = 0.f, q = 0.f;
      #pragma unroll
      for (int n = 0; n < 8; ++n){
        float v = acc[m][n][r];
        p += v; q += v * v;
      }
      p += __shfl_xor(p, 1);  q += __shfl_xor(q, 1);
      p += __shfl_xor(p, 2);  q += __shfl_xor(q, 2);
      p += __shfl_xor(p, 4);  q += __shfl_xor(q, 4);
      p += __shfl_xor(p, 8);  q += __shfl_xor(q, 8);
      if (lrow == 0){
        int row = m * 16 + quad * 4 + r;
        stats[(wave * 64 + row) * 2]     = p;
        stats[(wave * 64 + row) * 2 + 1] = q;
      }
    }
  asm volatile("s_waitcnt lgkmcnt(0)" ::: "memory");
  BARRIER();

  // 4 passes of 16 rows (pass = m): stats finalize + scatter + coalesced copy
  #pragma unroll
  for (int m = 0; m < 4; ++m){
    float meanr[4], rstdr[4];
    #pragma unroll
    for (int r = 0; r < 4; ++r){
      int row = m * 16 + quad * 4 + r;
      float S = 0.f, SS = 0.f;
      #pragma unroll
      for (int w = 0; w < 8; ++w){
        S  += stats[(w * 64 + row) * 2];
        SS += stats[(w * 64 + row) * 2 + 1];
      }
      float mean = S * (1.0f / 1024.0f);
      float var  = SS * (1.0f / 1024.0f) - mean * mean;
      meanr[r] = mean;
      rstdr[r] = rsqrtf(var + 1e-5f);
    }
    #pragma unroll
    for (int n = 0; n < 8; ++n){
      int col = wave * 128 + n * 16 + lrow;
      #pragma unroll
      for (int r = 0; r < 4; ++r){
        float v = (acc[m][n][r] - meanr[r]) * rstdr[r] * gv[n] + bv[n];
        *(float*)(smem + (quad * 4 + r) * 4096 + col * 4) = v;
      }
    }
    asm volatile("s_waitcnt lgkmcnt(0)" ::: "memory");
    BARRIER();
    // copy out: 16 rows x 256 chunks of 16B = 4096 chunks; thread t takes t + 512*i
    #pragma unroll
    for (int i = 0; i < 8; ++i){
      int c = i * 512 + tid;
      int row = c >> 8, cx = c & 255;
      uint4 u = *(const uint4*)(smem + row * 4096 + cx * 16);
      *(uint4*)(out + (rowBase + m * 16 + row) * 1024 + cx * 4) = u;
    }
    BARRIER();   // before next pass overwrites bounce region
  }
}

// ---------- per-position head-attention: LDS-free, barrier-free ----------
// (r5 version, measured; unchanged)
__global__ __launch_bounds__(256) void k_attention(const unsigned short* __restrict__ qkv,
                                                   unsigned short* __restrict__ aout){
  const int lane = threadIdx.x & 63;
  const int wave = threadIdx.x >> 6;
  const int pos  = blockIdx.x * 4 + wave;
  const int quad = lane >> 4, lidx = lane & 15;

  const unsigned short* src = qkv + (size_t)pos * 3072;

  f32x4 s = (f32x4){0.f, 0.f, 0.f, 0.f};
  #pragma unroll
  for (int kk = 0; kk < 2; ++kk){
    bf16x8 aK = *(const bf16x8*)(src + 1024 + lidx * 64 + kk * 32 + quad * 8);
    bf16x8 bQ = *(const bf16x8*)(src +        lidx * 64 + kk * 32 + quad * 8);
    s = __builtin_amdgcn_mfma_f32_16x16x32_bf16(aK, bQ, s, 0, 0, 0);
  }

  float v0 = s[0] * 0.125f, v1 = s[1] * 0.125f;
  float v2 = s[2] * 0.125f, v3 = s[3] * 0.125f;
  float m = fmaxf(fmaxf(v0, v1), fmaxf(v2, v3));
  m = fmaxf(m, __shfl_xor(m, 16));
  m = fmaxf(m, __shfl_xor(m, 32));
  float e0 = __expf(v0 - m), e1 = __expf(v1 - m);
  float e2 = __expf(v2 - m), e3 = __expf(v3 - m);
  float sum = e0 + e1 + e2 + e3;
  sum += __shfl_xor(sum, 16);
  sum += __shfl_xor(sum, 32);
  float inv = 1.0f / sum;
  unsigned P01 = (unsigned)f2bf_bits(e0 * inv) | ((unsigned)f2bf_bits(e1 * inv) << 16);
  unsigned P23 = (unsigned)f2bf_bits(e2 * inv) | ((unsigned)f2bf_bits(e3 * inv) << 16);

  int sA = ((quad * 32) + lidx) & 63;
  int sB = (sA + 16) & 63;
  unsigned w0 = (unsigned)__shfl((int)P01, sA);
  unsigned w1 = (unsigned)__shfl((int)P23, sA);
  unsigned w2 = (unsigned)__shfl((int)P01, sB);
  unsigned w3 = (unsigned)__shfl((int)P23, sB);
  if (quad >= 2){ w0 = 0u; w1 = 0u; w2 = 0u; w3 = 0u; }
  union { unsigned u[4]; bf16x8 v; } bp;
  bp.u[0] = w0; bp.u[1] = w1; bp.u[2] = w2; bp.u[3] = w3;

  const unsigned short* Vp = src + 2048;
  unsigned short* dst = aout + (size_t)pos * 1024;
  #pragma unroll
  for (int n4 = 0; n4 < 4; ++n4){
    union { unsigned short us[8]; bf16x8 v; } av;
    #pragma unroll
    for (int j = 0; j < 8; ++j){
      unsigned short rv = Vp[((quad * 8 + j) & 15) * 64 + n4 * 16 + lidx];
      av.us[j] = (quad < 2) ? rv : (unsigned short)0;
    }
    f32x4 o = __builtin_amdgcn_mfma_f32_16x16x32_bf16(
        av.v, bp.v, (f32x4){0.f, 0.f, 0.f, 0.f}, 0, 0, 0);
    unsigned lo = (unsigned)f2bf_bits(o[0]) | ((unsigned)f2bf_bits(o[1]) << 16);
    unsigned hi = (unsigned)f2bf_bits(o[2]) | ((unsigned)f2bf_bits(o[3]) << 16);
    uint2 st; st.x = lo; st.y = hi;
    *(uint2*)(dst + lidx * 64 + n4 * 16 + quad * 4) = st;
  }
}

extern "C" void kernel_launch(void* const* d_in, const int* in_sizes, int n_in,
                              void* d_out, int out_size, void* d_ws, size_t ws_size,
                              hipStream_t stream){
  const float* x     = (const float*)d_in[0];
  const float* Wq    = (const float*)d_in[1];
  const float* bq    = (const float*)d_in[2];
  const float* Wk    = (const float*)d_in[3];
  const float* bk    = (const float*)d_in[4];
  const float* Wv    = (const float*)d_in[5];
  const float* bv    = (const float*)d_in[6];
  const float* Wo    = (const float*)d_in[7];
  const float* bo    = (const float*)d_in[8];
  const float* gamma = (const float*)d_in[9];
  const float* beta  = (const float*)d_in[10];
  float* out = (float*)d_out;

  // workspace layout (bytes):
  //   [0, 6291456)            Wqkv^T bf16 (3072 x 1024)
  //   [6291456, 8388608)      Wo^T bf16  (1024 x 1024)
  //   [8388608, 75497472)     xb bf16 (32768 x 1024); reused as attn-out after GEMM1
  //   [75497472, 276824064)   qkv bf16 (32768 x 3072)
  char* ws = (char*)d_ws;
  unsigned short* Wqkv_t = (unsigned short*)ws;
  unsigned short* Wo_t   = (unsigned short*)(ws + 6291456);
  unsigned short* xb     = (unsigned short*)(ws + 8388608);
  unsigned short* qkv    = (unsigned short*)(ws + 75497472);
  unsigned short* aout   = xb;    // xb consumed by GEMM1 before attention writes

  // 1) x -> bf16
  k_convert_bf16<<<32768, 256, 0, stream>>>(x, xb, (MM * FFD) / 4);

  // 2) weight transposes (fp32 KxN -> bf16 NxK), one launch
  k_transpose4<<<dim3(32, 32, 4), 256, 0, stream>>>(Wq, Wk, Wv, Wo, Wqkv_t, Wo_t);

  // 3) QKV GEMM: (32768 x 1024) @ (1024 x 3072) -> bf16  (grid 12x128 = 1536 blocks)
  k_gemm_bt<<<dim3(NQKV / 256, MM / 256), 512, 0, stream>>>(
      xb, Wqkv_t, bq, bk, bv, qkv, MM, NQKV, FFD);

  // 4) per-position head attention (LDS-free MFMA)
  k_attention<<<MM / 4, 256, 0, stream>>>(qkv, aout);

  // 5) fused output GEMM + bias + LayerNorm -> fp32 d_out (512 blocks of 64 rows)
  k_gemm2_ln<<<MM / 64, 512, 0, stream>>>(aout, Wo_t, bo, gamma, beta, out);
}

// Round 10
// 688.943 us; speedup vs baseline: 1.0123x; 1.0123x over previous
//
#include <hip/hip_runtime.h>
#include <hip/hip_bf16.h>
#include <stdint.h>

// Problem constants
#define MM   32768   // B*S
#define FFD  1024    // F
#define NQKV 3072    // 3*F

typedef __bf16 bf16x8 __attribute__((ext_vector_type(8)));
typedef float  f32x4  __attribute__((ext_vector_type(4)));

__device__ __forceinline__ unsigned short f2bf_bits(float f){
  __hip_bfloat16 h = __float2bfloat16(f);
  unsigned short u;
  __builtin_memcpy(&u, &h, 2);
  return u;
}

__device__ __forceinline__ void gld16(const void* g, void* l){
  const unsigned int* gu = (const unsigned int*)g;
  unsigned int* lu = (unsigned int*)l;
  __builtin_amdgcn_global_load_lds(
      (const __attribute__((address_space(1))) unsigned int*)gu,
      (__attribute__((address_space(3))) unsigned int*)lu,
      16, 0, 0);
}

// Raw barrier (no vmcnt(0) auto-drain like __syncthreads) + compiler memory fence
#define BARRIER() do { asm volatile("" ::: "memory"); \
                       __builtin_amdgcn_s_barrier();  \
                       asm volatile("" ::: "memory"); } while(0)

// ---------- convert fp32 -> bf16, 4 elems/thread ----------
__global__ __launch_bounds__(256) void k_convert_bf16(const float* __restrict__ in,
                                                      unsigned short* __restrict__ out,
                                                      int n4){
  int i = blockIdx.x * 256 + threadIdx.x;
  if (i >= n4) return;
  float4 v = ((const float4*)in)[i];
  ushort4 r;
  r.x = f2bf_bits(v.x); r.y = f2bf_bits(v.y);
  r.z = f2bf_bits(v.z); r.w = f2bf_bits(v.w);
  ((ushort4*)out)[i] = r;
}

// ---------- all 4 weight transposes in one launch (z picks matrix) ----------
__global__ __launch_bounds__(256) void k_transpose4(const float* __restrict__ Wq,
                                                    const float* __restrict__ Wk,
                                                    const float* __restrict__ Wv,
                                                    const float* __restrict__ Wo,
                                                    unsigned short* __restrict__ Wqkv_t,
                                                    unsigned short* __restrict__ Wo_t){
  __shared__ float tile[32][33];
  const float* in;
  unsigned short* out;
  switch (blockIdx.z){
    case 0:  in = Wq; out = Wqkv_t;               break;
    case 1:  in = Wk; out = Wqkv_t + 1024 * 1024; break;
    case 2:  in = Wv; out = Wqkv_t + 2048 * 1024; break;
    default: in = Wo; out = Wo_t;                 break;
  }
  int bc = blockIdx.x * 32, br = blockIdx.y * 32;
  int tx = threadIdx.x & 31, ty = threadIdx.x >> 5;
  #pragma unroll
  for (int j = 0; j < 32; j += 8)
    tile[ty + j][tx] = in[(size_t)(br + ty + j) * 1024 + bc + tx];
  __syncthreads();
  #pragma unroll
  for (int j = 0; j < 32; j += 8)
    out[(size_t)(bc + ty + j) * 1024 + br + tx] = f2bf_bits(tile[tx][ty + j]);
}

// ---------- GEMM1: C(MxN) = A(MxK)*Bt(NxK)^T + bias -> bf16 ----------
// r2-verified structure (best measured: ~228us, 0 conflicts, 189MB fetch):
// 256x256 tile, BK=32, 512 threads (8 waves 2Mx4N), ring-4 LDS staged 3 tiles
// ahead, ONE counted {s_waitcnt vmcnt(8); s_barrier} per K-tile, free-drift
// body, LDS-bounce bf16 epilogue (ideal WRITE_SIZE).
__global__ __launch_bounds__(512, 2) void k_gemm_bt(
    const unsigned short* __restrict__ A,
    const unsigned short* __restrict__ Bt,
    const float* __restrict__ b0, const float* __restrict__ b1, const float* __restrict__ b2,
    unsigned short* __restrict__ Cout, int M, int N, int K)
{
  __shared__ alignas(16) char smem[131072];

  const int tid  = threadIdx.x;
  const int lane = tid & 63;
  const int wave = tid >> 6;
  const int wr = wave >> 2, wc = wave & 3;       // 2 x 4 wave grid
  const int quad = lane >> 4, lrow = lane & 15;
  const int sa = ((lrow >> 1) & 3) << 4;         // read-side XOR swizzle bits

  // XCD-aware bijective block swizzle (grid multiple of 8)
  const int nwgx = gridDim.x;
  int nwg = nwgx * gridDim.y;
  int bid = blockIdx.y * nwgx + blockIdx.x;
  int cpx = nwg >> 3;
  int nid = (bid & 7) * cpx + (bid >> 3);
  int by = nid / nwgx;
  int bx = nid - by * nwgx;

  const long rowBase = (long)by * 256;
  const long colBase = (long)bx * 256;

  f32x4 acc[8][4];
  #pragma unroll
  for (int i = 0; i < 8; i++)
    #pragma unroll
    for (int j = 0; j < 4; j++)
      acc[i][j] = (f32x4){0.f, 0.f, 0.f, 0.f};

  const int swz8 = 8 * ((tid & 3) ^ ((tid >> 3) & 3));
  const unsigned short* gA = A  + (rowBase + (tid >> 2)) * (long)K + swz8;
  const unsigned short* gB = Bt + (colBase + (tid >> 2)) * (long)K + swz8;
  const long hstep = 128L * K;

  const int nk = K >> 5;

  #pragma unroll
  for (int tt = 0; tt < 3; ++tt){
    char* nb = smem + tt * 32768;
    gld16(gA + tt * 32,         nb +         tid * 16);
    gld16(gA + tt * 32 + hstep, nb +  8192 + tid * 16);
    gld16(gB + tt * 32,         nb + 16384 + tid * 16);
    gld16(gB + tt * 32 + hstep, nb + 24576 + tid * 16);
  }

  for (int t = 0; t < nk; ++t){
    if (t <= nk - 3)      asm volatile("s_waitcnt vmcnt(8)" ::: "memory");
    else if (t == nk - 2) asm volatile("s_waitcnt vmcnt(4)" ::: "memory");
    else                  asm volatile("s_waitcnt vmcnt(0)" ::: "memory");
    BARRIER();

    char* buf = smem + (t & 3) * 32768;
    if (t < nk - 3){
      char* nb = smem + ((t + 3) & 3) * 32768;
      const unsigned short* sA = gA + (long)(t + 3) * 32;
      const unsigned short* sB = gB + (long)(t + 3) * 32;
      gld16(sA,         nb +         tid * 16);
      gld16(sA + hstep, nb +  8192 + tid * 16);
      gld16(sB,         nb + 16384 + tid * 16);
      gld16(sB + hstep, nb + 24576 + tid * 16);
    }

    bf16x8 bfr[4];
    const char* bb = buf + 16384 + wc * 4096 + lrow * 64 + ((quad * 16) ^ sa);
    #pragma unroll
    for (int n = 0; n < 4; ++n)
      bfr[n] = *(const bf16x8*)(bb + n * 1024);

    #pragma unroll
    for (int p = 0; p < 2; ++p){
      bf16x8 af[4];
      const char* ab = buf + wr * 8192 + p * 4096 + lrow * 64 + ((quad * 16) ^ sa);
      #pragma unroll
      for (int f = 0; f < 4; ++f)
        af[f] = *(const bf16x8*)(ab + f * 1024);
      __builtin_amdgcn_s_setprio(1);
      #pragma unroll
      for (int f = 0; f < 4; ++f)
        #pragma unroll
        for (int n = 0; n < 4; ++n)
          acc[p * 4 + f][n] =
              __builtin_amdgcn_mfma_f32_16x16x32_bf16(af[f], bfr[n], acc[p * 4 + f][n], 0, 0, 0);
      __builtin_amdgcn_s_setprio(0);
    }
  }

  // epilogue: LDS-bounce -> coalesced 16B bf16 stores
  BARRIER();
  #pragma unroll
  for (int n = 0; n < 4; ++n){
    int lcol = wc * 64 + n * 16 + lrow;
    long col = colBase + lcol;
    const float* bp = (col < 1024) ? b0 : ((col < 2048) ? b1 : b2);
    float bias = bp[col & 1023];
    #pragma unroll
    for (int m = 0; m < 8; ++m){
      int row0 = wr * 128 + (m >> 2) * 64 + (m & 3) * 16 + quad * 4;
      int sw = ((row0 >> 2) & 3) << 5;
      #pragma unroll
      for (int r = 0; r < 4; ++r){
        float v = acc[m][n][r] + bias;
        int byte = (row0 + r) * 512 + ((lcol * 2) ^ sw);
        *(unsigned short*)(smem + byte) = f2bf_bits(v);
      }
    }
  }
  asm volatile("s_waitcnt lgkmcnt(0)" ::: "memory");
  BARRIER();
  #pragma unroll
  for (int i = 0; i < 16; ++i){
    int c = i * 512 + tid;
    int row = c >> 5, cidx = c & 31;
    int rb = (cidx ^ (((row >> 2) & 3) << 1)) * 16;
    uint4 u = *(const uint4*)(smem + row * 512 + rb);
    *(uint4*)(Cout + (rowBase + row) * (long)N + colBase + cidx * 8) = u;
  }
}

// ---------- fused GEMM2 + bias + LayerNorm -> fp32 out ----------
// Tile 64 rows x FULL 1024 cols, 512 threads (8 waves x 128 cols), acc[4][8].
// A staged in a 3x4KB LDS ring via gld16. B (Wo^T, L2-resident) read from
// global into a REGISTER DOUBLE-BUFFER: iter t consumes B(t) (loaded during
// iter t-1) and issues B(t+1) -- so B's L2 latency hides under MFMA(t)+barrier
// instead of stalling pre-MFMA every step (the r9 regression). vmcnt derived
// inductively: top-of-iter queue = [A(t), 8xB(t), A(t+1)] -> vmcnt(1)
// certifies A(t)+B(t), keeps A(t+1) in flight; last iter vmcnt(0).
// Two NAMED reg arrays + unroll-by-2 macro (no runtime-indexed reg arrays).
// LN stats from accumulators (shfl + LDS cross-wave reduce, no atomics);
// fp32 written straight to d_out via 4-pass LDS bounce (coalesced 16B).
__global__ __launch_bounds__(512) void k_gemm2_ln(
    const unsigned short* __restrict__ A,
    const unsigned short* __restrict__ Bt,
    const float* __restrict__ bo,
    const float* __restrict__ gamma, const float* __restrict__ beta,
    float* __restrict__ out)
{
  __shared__ alignas(16) char smem[69632];   // [0,64K) bounce / [0,12K) A-ring; [64K,68K) stats

  const int tid  = threadIdx.x;
  const int lane = tid & 63;
  const int wave = tid >> 6;                 // wave covers cols wave*128..+128
  const int quad = lane >> 4, lrow = lane & 15;
  const int csw  = (quad ^ ((lrow >> 1) & 3)) << 4;   // r2-style swizzle (2-way max)

  // XCD swizzle (512 blocks, %8==0)
  int nwg = gridDim.x;
  int bid = blockIdx.x;
  int cpx = nwg >> 3;
  int nid = (bid & 7) * cpx + (bid >> 3);
  const long rowBase = (long)nid * 64;

  f32x4 acc[4][8];
  #pragma unroll
  for (int i = 0; i < 4; i++)
    #pragma unroll
    for (int j = 0; j < 8; j++)
      acc[i][j] = (f32x4){0.f, 0.f, 0.f, 0.f};

  // A staging: threads 0-255 cover (row = tid>>2 in [0,64), chunk tid&3),
  // global chunk pre-swizzled (tid&3)^((tid>>3)&3) so linear LDS + csw reads match.
  const int swz8 = 8 * ((tid & 3) ^ ((tid >> 3) & 3));
  const unsigned short* gA = A + (rowBase + (tid >> 2)) * 1024L + swz8;
  const int t16 = tid * 16;
  const int nk = 32;   // K=1024 / 32

  // B fragment base: row (output col) for frag n is wave*128 + n*16 + lrow
  const unsigned short* gBf = Bt + (size_t)(wave * 128 + lrow) * 1024 + quad * 8;

  bf16x8 bfrA[8], bfrB[8];

  // prologue: B(0) -> bfrA; A(0),A(1) -> ring slots 0,1
  #pragma unroll
  for (int n = 0; n < 8; ++n)
    bfrA[n] = *(const bf16x8*)(gBf + (size_t)(n * 16) * 1024);
  if (tid < 256){
    gld16(gA,      smem        + t16);
    gld16(gA + 32, smem + 4096 + t16);
  }

  #define G2_STEP(t, CUR, NXT)                                                  \
  {                                                                             \
    if ((t) == nk - 1) asm volatile("s_waitcnt vmcnt(0)" ::: "memory");         \
    else               asm volatile("s_waitcnt vmcnt(1)" ::: "memory");         \
    BARRIER();                                                                  \
    const char* buf = smem + ((t) % 3) * 4096;                                  \
    bf16x8 af[4];                                                               \
    _Pragma("unroll")                                                           \
    for (int m = 0; m < 4; ++m)                                                 \
      af[m] = *(const bf16x8*)(buf + (m * 16 + lrow) * 64 + csw);               \
    if ((t) + 1 < nk){                                                          \
      _Pragma("unroll")                                                         \
      for (int n = 0; n < 8; ++n)                                               \
        NXT[n] = *(const bf16x8*)(gBf + (size_t)(n * 16) * 1024 + ((t) + 1) * 32); \
    }                                                                           \
    if ((t) + 2 < nk && tid < 256)                                              \
      gld16(gA + (long)((t) + 2) * 32, smem + (((t) + 2) % 3) * 4096 + t16);    \
    __builtin_amdgcn_s_setprio(1);                                              \
    _Pragma("unroll")                                                           \
    for (int m = 0; m < 4; ++m)                                                 \
      _Pragma("unroll")                                                         \
      for (int n = 0; n < 8; ++n)                                               \
        acc[m][n] = __builtin_amdgcn_mfma_f32_16x16x32_bf16(af[m], CUR[n], acc[m][n], 0, 0, 0); \
    __builtin_amdgcn_s_setprio(0);                                              \
  }

  for (int t = 0; t < nk; t += 2){
    G2_STEP(t,     bfrA, bfrB);
    G2_STEP(t + 1, bfrB, bfrA);
  }
  #undef G2_STEP

  // ---------------- fused bias + LN epilogue ----------------
  // C/D layout: col = lrow (per n-frag), row = m*16 + quad*4 + r.
  float gv[8], bv[8];
  #pragma unroll
  for (int n = 0; n < 8; ++n){
    int col = wave * 128 + n * 16 + lrow;
    float bias = bo[col];
    gv[n] = gamma[col]; bv[n] = beta[col];
    #pragma unroll
    for (int m = 0; m < 4; ++m)
      #pragma unroll
      for (int r = 0; r < 4; ++r)
        acc[m][n][r] += bias;
  }

  // per-row partial sums over this wave's 128 cols -> stats LDS
  float* stats = (float*)(smem + 65536);   // [wave][64 rows][2]
  #pragma unroll
  for (int m = 0; m < 4; ++m)
    #pragma unroll
    for (int r = 0; r < 4; ++r){
      float p = 0.f, q = 0.f;
      #pragma unroll
      for (int n = 0; n < 8; ++n){
        float v = acc[m][n][r];
        p += v; q += v * v;
      }
      p += __shfl_xor(p, 1);  q += __shfl_xor(q, 1);
      p += __shfl_xor(p, 2);  q += __shfl_xor(q, 2);
      p += __shfl_xor(p, 4);  q += __shfl_xor(q, 4);
      p += __shfl_xor(p, 8);  q += __shfl_xor(q, 8);
      if (lrow == 0){
        int row = m * 16 + quad * 4 + r;
        stats[(wave * 64 + row) * 2]     = p;
        stats[(wave * 64 + row) * 2 + 1] = q;
      }
    }
  asm volatile("s_waitcnt lgkmcnt(0)" ::: "memory");
  BARRIER();

  // 4 passes of 16 rows (pass = m): stats finalize + scatter + coalesced copy
  #pragma unroll
  for (int m = 0; m < 4; ++m){
    float meanr[4], rstdr[4];
    #pragma unroll
    for (int r = 0; r < 4; ++r){
      int row = m * 16 + quad * 4 + r;
      float S = 0.f, SS = 0.f;
      #pragma unroll
      for (int w = 0; w < 8; ++w){
        S  += stats[(w * 64 + row) * 2];
        SS += stats[(w * 64 + row) * 2 + 1];
      }
      float mean = S * (1.0f / 1024.0f);
      float var  = SS * (1.0f / 1024.0f) - mean * mean;
      meanr[r] = mean;
      rstdr[r] = rsqrtf(var + 1e-5f);
    }
    #pragma unroll
    for (int n = 0; n < 8; ++n){
      int col = wave * 128 + n * 16 + lrow;
      #pragma unroll
      for (int r = 0; r < 4; ++r){
        float v = (acc[m][n][r] - meanr[r]) * rstdr[r] * gv[n] + bv[n];
        *(float*)(smem + (quad * 4 + r) * 4096 + col * 4) = v;
      }
    }
    asm volatile("s_waitcnt lgkmcnt(0)" ::: "memory");
    BARRIER();
    // copy out: 16 rows x 256 chunks of 16B = 4096 chunks; thread t takes t + 512*i
    #pragma unroll
    for (int i = 0; i < 8; ++i){
      int c = i * 512 + tid;
      int row = c >> 8, cx = c & 255;
      uint4 u = *(const uint4*)(smem + row * 4096 + cx * 16);
      *(uint4*)(out + (rowBase + m * 16 + row) * 1024 + cx * 4) = u;
    }
    BARRIER();   // before next pass overwrites bounce region
  }
}

// ---------- per-position head-attention: LDS-free, barrier-free ----------
// (r5 version, measured; unchanged)
__global__ __launch_bounds__(256) void k_attention(const unsigned short* __restrict__ qkv,
                                                   unsigned short* __restrict__ aout){
  const int lane = threadIdx.x & 63;
  const int wave = threadIdx.x >> 6;
  const int pos  = blockIdx.x * 4 + wave;
  const int quad = lane >> 4, lidx = lane & 15;

  const unsigned short* src = qkv + (size_t)pos * 3072;

  f32x4 s = (f32x4){0.f, 0.f, 0.f, 0.f};
  #pragma unroll
  for (int kk = 0; kk < 2; ++kk){
    bf16x8 aK = *(const bf16x8*)(src + 1024 + lidx * 64 + kk * 32 + quad * 8);
    bf16x8 bQ = *(const bf16x8*)(src +        lidx * 64 + kk * 32 + quad * 8);
    s = __builtin_amdgcn_mfma_f32_16x16x32_bf16(aK, bQ, s, 0, 0, 0);
  }

  float v0 = s[0] * 0.125f, v1 = s[1] * 0.125f;
  float v2 = s[2] * 0.125f, v3 = s[3] * 0.125f;
  float m = fmaxf(fmaxf(v0, v1), fmaxf(v2, v3));
  m = fmaxf(m, __shfl_xor(m, 16));
  m = fmaxf(m, __shfl_xor(m, 32));
  float e0 = __expf(v0 - m), e1 = __expf(v1 - m);
  float e2 = __expf(v2 - m), e3 = __expf(v3 - m);
  float sum = e0 + e1 + e2 + e3;
  sum += __shfl_xor(sum, 16);
  sum += __shfl_xor(sum, 32);
  float inv = 1.0f / sum;
  unsigned P01 = (unsigned)f2bf_bits(e0 * inv) | ((unsigned)f2bf_bits(e1 * inv) << 16);
  unsigned P23 = (unsigned)f2bf_bits(e2 * inv) | ((unsigned)f2bf_bits(e3 * inv) << 16);

  int sA = ((quad * 32) + lidx) & 63;
  int sB = (sA + 16) & 63;
  unsigned w0 = (unsigned)__shfl((int)P01, sA);
  unsigned w1 = (unsigned)__shfl((int)P23, sA);
  unsigned w2 = (unsigned)__shfl((int)P01, sB);
  unsigned w3 = (unsigned)__shfl((int)P23, sB);
  if (quad >= 2){ w0 = 0u; w1 = 0u; w2 = 0u; w3 = 0u; }
  union { unsigned u[4]; bf16x8 v; } bp;
  bp.u[0] = w0; bp.u[1] = w1; bp.u[2] = w2; bp.u[3] = w3;

  const unsigned short* Vp = src + 2048;
  unsigned short* dst = aout + (size_t)pos * 1024;
  #pragma unroll
  for (int n4 = 0; n4 < 4; ++n4){
    union { unsigned short us[8]; bf16x8 v; } av;
    #pragma unroll
    for (int j = 0; j < 8; ++j){
      unsigned short rv = Vp[((quad * 8 + j) & 15) * 64 + n4 * 16 + lidx];
      av.us[j] = (quad < 2) ? rv : (unsigned short)0;
    }
    f32x4 o = __builtin_amdgcn_mfma_f32_16x16x32_bf16(
        av.v, bp.v, (f32x4){0.f, 0.f, 0.f, 0.f}, 0, 0, 0);
    unsigned lo = (unsigned)f2bf_bits(o[0]) | ((unsigned)f2bf_bits(o[1]) << 16);
    unsigned hi = (unsigned)f2bf_bits(o[2]) | ((unsigned)f2bf_bits(o[3]) << 16);
    uint2 st; st.x = lo; st.y = hi;
    *(uint2*)(dst + lidx * 64 + n4 * 16 + quad * 4) = st;
  }
}

extern "C" void kernel_launch(void* const* d_in, const int* in_sizes, int n_in,
                              void* d_out, int out_size, void* d_ws, size_t ws_size,
                              hipStream_t stream){
  const float* x     = (const float*)d_in[0];
  const float* Wq    = (const float*)d_in[1];
  const float* bq    = (const float*)d_in[2];
  const float* Wk    = (const float*)d_in[3];
  const float* bk    = (const float*)d_in[4];
  const float* Wv    = (const float*)d_in[5];
  const float* bv    = (const float*)d_in[6];
  const float* Wo    = (const float*)d_in[7];
  const float* bo    = (const float*)d_in[8];
  const float* gamma = (const float*)d_in[9];
  const float* beta  = (const float*)d_in[10];
  float* out = (float*)d_out;

  // workspace layout (bytes):
  //   [0, 6291456)            Wqkv^T bf16 (3072 x 1024)
  //   [6291456, 8388608)      Wo^T bf16  (1024 x 1024)
  //   [8388608, 75497472)     xb bf16 (32768 x 1024); reused as attn-out after GEMM1
  //   [75497472, 276824064)   qkv bf16 (32768 x 3072)
  char* ws = (char*)d_ws;
  unsigned short* Wqkv_t = (unsigned short*)ws;
  unsigned short* Wo_t   = (unsigned short*)(ws + 6291456);
  unsigned short* xb     = (unsigned short*)(ws + 8388608);
  unsigned short* qkv    = (unsigned short*)(ws + 75497472);
  unsigned short* aout   = xb;    // xb consumed by GEMM1 before attention writes

  // 1) x -> bf16
  k_convert_bf16<<<32768, 256, 0, stream>>>(x, xb, (MM * FFD) / 4);

  // 2) weight transposes (fp32 KxN -> bf16 NxK), one launch
  k_transpose4<<<dim3(32, 32, 4), 256, 0, stream>>>(Wq, Wk, Wv, Wo, Wqkv_t, Wo_t);

  // 3) QKV GEMM: (32768 x 1024) @ (1024 x 3072) -> bf16  (grid 12x128 = 1536 blocks)
  k_gemm_bt<<<dim3(NQKV / 256, MM / 256), 512, 0, stream>>>(
      xb, Wqkv_t, bq, bk, bv, qkv, MM, NQKV, FFD);

  // 4) per-position head attention (LDS-free MFMA)
  k_attention<<<MM / 4, 256, 0, stream>>>(qkv, aout);

  // 5) fused output GEMM + bias + LayerNorm -> fp32 d_out (512 blocks of 64 rows)
  k_gemm2_ln<<<MM / 64, 512, 0, stream>>>(aout, Wo_t, bo, gamma, beta, out);
}

// Round 12
// 611.292 us; speedup vs baseline: 1.1409x; 1.1270x over previous
//
#include <hip/hip_runtime.h>
#include <hip/hip_bf16.h>
#include <stdint.h>

// Problem constants
#define MM   32768   // B*S
#define FFD  1024    // F
#define NQKV 3072    // 3*F

typedef __bf16 bf16x8 __attribute__((ext_vector_type(8)));
typedef float  f32x4  __attribute__((ext_vector_type(4)));

__device__ __forceinline__ unsigned short f2bf_bits(float f){
  __hip_bfloat16 h = __float2bfloat16(f);
  unsigned short u;
  __builtin_memcpy(&u, &h, 2);
  return u;
}

__device__ __forceinline__ float bf2f(unsigned short u){
  unsigned v = ((unsigned)u) << 16;
  float f;
  __builtin_memcpy(&f, &v, 4);
  return f;
}

__device__ __forceinline__ void gld16(const void* g, void* l){
  const unsigned int* gu = (const unsigned int*)g;
  unsigned int* lu = (unsigned int*)l;
  __builtin_amdgcn_global_load_lds(
      (const __attribute__((address_space(1))) unsigned int*)gu,
      (__attribute__((address_space(3))) unsigned int*)lu,
      16, 0, 0);
}

// Raw barrier (no vmcnt(0) auto-drain like __syncthreads) + compiler memory fence
#define BARRIER() do { asm volatile("" ::: "memory"); \
                       __builtin_amdgcn_s_barrier();  \
                       asm volatile("" ::: "memory"); } while(0)

// ---------- convert fp32 -> bf16, 4 elems/thread ----------
__global__ __launch_bounds__(256) void k_convert_bf16(const float* __restrict__ in,
                                                      unsigned short* __restrict__ out,
                                                      int n4){
  int i = blockIdx.x * 256 + threadIdx.x;
  if (i >= n4) return;
  float4 v = ((const float4*)in)[i];
  ushort4 r;
  r.x = f2bf_bits(v.x); r.y = f2bf_bits(v.y);
  r.z = f2bf_bits(v.z); r.w = f2bf_bits(v.w);
  ((ushort4*)out)[i] = r;
}

// ---------- all 4 weight transposes in one launch (z picks matrix) ----------
__global__ __launch_bounds__(256) void k_transpose4(const float* __restrict__ Wq,
                                                    const float* __restrict__ Wk,
                                                    const float* __restrict__ Wv,
                                                    const float* __restrict__ Wo,
                                                    unsigned short* __restrict__ Wqkv_t,
                                                    unsigned short* __restrict__ Wo_t){
  __shared__ float tile[32][33];
  const float* in;
  unsigned short* out;
  switch (blockIdx.z){
    case 0:  in = Wq; out = Wqkv_t;               break;
    case 1:  in = Wk; out = Wqkv_t + 1024 * 1024; break;
    case 2:  in = Wv; out = Wqkv_t + 2048 * 1024; break;
    default: in = Wo; out = Wo_t;                 break;
  }
  int bc = blockIdx.x * 32, br = blockIdx.y * 32;
  int tx = threadIdx.x & 31, ty = threadIdx.x >> 5;
  #pragma unroll
  for (int j = 0; j < 32; j += 8)
    tile[ty + j][tx] = in[(size_t)(br + ty + j) * 1024 + bc + tx];
  __syncthreads();
  #pragma unroll
  for (int j = 0; j < 32; j += 8)
    out[(size_t)(bc + ty + j) * 1024 + br + tx] = f2bf_bits(tile[tx][ty + j]);
}

// ---------- bf16 MFMA GEMM: C(MxN) = A(MxK)*Bt(NxK)^T + bias -> bf16 ----------
// r2-verified structure (best measured: ~229us GEMM1, 0 conflicts, 189MB fetch):
// 256x256 tile, BK=32, 512 threads (8 waves 2Mx4N), ring-4 LDS staged 3 tiles
// ahead, ONE counted {s_waitcnt vmcnt(8); s_barrier} per K-tile, free-drift
// body, LDS-bounce bf16 epilogue (ideal WRITE_SIZE). Used for BOTH GEMMs.
__global__ __launch_bounds__(512, 2) void k_gemm_bt(
    const unsigned short* __restrict__ A,
    const unsigned short* __restrict__ Bt,
    const float* __restrict__ b0, const float* __restrict__ b1, const float* __restrict__ b2,
    unsigned short* __restrict__ Cout, int M, int N, int K)
{
  __shared__ alignas(16) char smem[131072];

  const int tid  = threadIdx.x;
  const int lane = tid & 63;
  const int wave = tid >> 6;
  const int wr = wave >> 2, wc = wave & 3;       // 2 x 4 wave grid
  const int quad = lane >> 4, lrow = lane & 15;
  const int sa = ((lrow >> 1) & 3) << 4;         // read-side XOR swizzle bits

  // XCD-aware bijective block swizzle (grid multiple of 8)
  const int nwgx = gridDim.x;
  int nwg = nwgx * gridDim.y;
  int bid = blockIdx.y * nwgx + blockIdx.x;
  int cpx = nwg >> 3;
  int nid = (bid & 7) * cpx + (bid >> 3);
  int by = nid / nwgx;
  int bx = nid - by * nwgx;

  const long rowBase = (long)by * 256;
  const long colBase = (long)bx * 256;

  f32x4 acc[8][4];
  #pragma unroll
  for (int i = 0; i < 8; i++)
    #pragma unroll
    for (int j = 0; j < 4; j++)
      acc[i][j] = (f32x4){0.f, 0.f, 0.f, 0.f};

  const int swz8 = 8 * ((tid & 3) ^ ((tid >> 3) & 3));
  const unsigned short* gA = A  + (rowBase + (tid >> 2)) * (long)K + swz8;
  const unsigned short* gB = Bt + (colBase + (tid >> 2)) * (long)K + swz8;
  const long hstep = 128L * K;

  const int nk = K >> 5;

  #pragma unroll
  for (int tt = 0; tt < 3; ++tt){
    char* nb = smem + tt * 32768;
    gld16(gA + tt * 32,         nb +         tid * 16);
    gld16(gA + tt * 32 + hstep, nb +  8192 + tid * 16);
    gld16(gB + tt * 32,         nb + 16384 + tid * 16);
    gld16(gB + tt * 32 + hstep, nb + 24576 + tid * 16);
  }

  for (int t = 0; t < nk; ++t){
    if (t <= nk - 3)      asm volatile("s_waitcnt vmcnt(8)" ::: "memory");
    else if (t == nk - 2) asm volatile("s_waitcnt vmcnt(4)" ::: "memory");
    else                  asm volatile("s_waitcnt vmcnt(0)" ::: "memory");
    BARRIER();

    char* buf = smem + (t & 3) * 32768;
    if (t < nk - 3){
      char* nb = smem + ((t + 3) & 3) * 32768;
      const unsigned short* sA = gA + (long)(t + 3) * 32;
      const unsigned short* sB = gB + (long)(t + 3) * 32;
      gld16(sA,         nb +         tid * 16);
      gld16(sA + hstep, nb +  8192 + tid * 16);
      gld16(sB,         nb + 16384 + tid * 16);
      gld16(sB + hstep, nb + 24576 + tid * 16);
    }

    bf16x8 bfr[4];
    const char* bb = buf + 16384 + wc * 4096 + lrow * 64 + ((quad * 16) ^ sa);
    #pragma unroll
    for (int n = 0; n < 4; ++n)
      bfr[n] = *(const bf16x8*)(bb + n * 1024);

    #pragma unroll
    for (int p = 0; p < 2; ++p){
      bf16x8 af[4];
      const char* ab = buf + wr * 8192 + p * 4096 + lrow * 64 + ((quad * 16) ^ sa);
      #pragma unroll
      for (int f = 0; f < 4; ++f)
        af[f] = *(const bf16x8*)(ab + f * 1024);
      __builtin_amdgcn_s_setprio(1);
      #pragma unroll
      for (int f = 0; f < 4; ++f)
        #pragma unroll
        for (int n = 0; n < 4; ++n)
          acc[p * 4 + f][n] =
              __builtin_amdgcn_mfma_f32_16x16x32_bf16(af[f], bfr[n], acc[p * 4 + f][n], 0, 0, 0);
      __builtin_amdgcn_s_setprio(0);
    }
  }

  // epilogue: LDS-bounce -> coalesced 16B bf16 stores
  BARRIER();
  #pragma unroll
  for (int n = 0; n < 4; ++n){
    int lcol = wc * 64 + n * 16 + lrow;
    long col = colBase + lcol;
    const float* bp = (col < 1024) ? b0 : ((col < 2048) ? b1 : b2);
    float bias = bp[col & 1023];
    #pragma unroll
    for (int m = 0; m < 8; ++m){
      int row0 = wr * 128 + (m >> 2) * 64 + (m & 3) * 16 + quad * 4;
      int sw = ((row0 >> 2) & 3) << 5;
      #pragma unroll
      for (int r = 0; r < 4; ++r){
        float v = acc[m][n][r] + bias;
        int byte = (row0 + r) * 512 + ((lcol * 2) ^ sw);
        *(unsigned short*)(smem + byte) = f2bf_bits(v);
      }
    }
  }
  asm volatile("s_waitcnt lgkmcnt(0)" ::: "memory");
  BARRIER();
  #pragma unroll
  for (int i = 0; i < 16; ++i){
    int c = i * 512 + tid;
    int row = c >> 5, cidx = c & 31;
    int rb = (cidx ^ (((row >> 2) & 3) << 1)) * 16;
    uint4 u = *(const uint4*)(smem + row * 512 + rb);
    *(uint4*)(Cout + (rowBase + row) * (long)N + colBase + cidx * 8) = u;
  }
}

// ---------- per-position head-attention: LDS-free, barrier-free ----------
// (r5 version, measured; unchanged)
__global__ __launch_bounds__(256) void k_attention(const unsigned short* __restrict__ qkv,
                                                   unsigned short* __restrict__ aout){
  const int lane = threadIdx.x & 63;
  const int wave = threadIdx.x >> 6;
  const int pos  = blockIdx.x * 4 + wave;
  const int quad = lane >> 4, lidx = lane & 15;

  const unsigned short* src = qkv + (size_t)pos * 3072;

  f32x4 s = (f32x4){0.f, 0.f, 0.f, 0.f};
  #pragma unroll
  for (int kk = 0; kk < 2; ++kk){
    bf16x8 aK = *(const bf16x8*)(src + 1024 + lidx * 64 + kk * 32 + quad * 8);
    bf16x8 bQ = *(const bf16x8*)(src +        lidx * 64 + kk * 32 + quad * 8);
    s = __builtin_amdgcn_mfma_f32_16x16x32_bf16(aK, bQ, s, 0, 0, 0);
  }

  float v0 = s[0] * 0.125f, v1 = s[1] * 0.125f;
  float v2 = s[2] * 0.125f, v3 = s[3] * 0.125f;
  float m = fmaxf(fmaxf(v0, v1), fmaxf(v2, v3));
  m = fmaxf(m, __shfl_xor(m, 16));
  m = fmaxf(m, __shfl_xor(m, 32));
  float e0 = __expf(v0 - m), e1 = __expf(v1 - m);
  float e2 = __expf(v2 - m), e3 = __expf(v3 - m);
  float sum = e0 + e1 + e2 + e3;
  sum += __shfl_xor(sum, 16);
  sum += __shfl_xor(sum, 32);
  float inv = 1.0f / sum;
  unsigned P01 = (unsigned)f2bf_bits(e0 * inv) | ((unsigned)f2bf_bits(e1 * inv) << 16);
  unsigned P23 = (unsigned)f2bf_bits(e2 * inv) | ((unsigned)f2bf_bits(e3 * inv) << 16);

  int sA = ((quad * 32) + lidx) & 63;
  int sB = (sA + 16) & 63;
  unsigned w0 = (unsigned)__shfl((int)P01, sA);
  unsigned w1 = (unsigned)__shfl((int)P23, sA);
  unsigned w2 = (unsigned)__shfl((int)P01, sB);
  unsigned w3 = (unsigned)__shfl((int)P23, sB);
  if (quad >= 2){ w0 = 0u; w1 = 0u; w2 = 0u; w3 = 0u; }
  union { unsigned u[4]; bf16x8 v; } bp;
  bp.u[0] = w0; bp.u[1] = w1; bp.u[2] = w2; bp.u[3] = w3;

  const unsigned short* Vp = src + 2048;
  unsigned short* dst = aout + (size_t)pos * 1024;
  #pragma unroll
  for (int n4 = 0; n4 < 4; ++n4){
    union { unsigned short us[8]; bf16x8 v; } av;
    #pragma unroll
    for (int j = 0; j < 8; ++j){
      unsigned short rv = Vp[((quad * 8 + j) & 15) * 64 + n4 * 16 + lidx];
      av.us[j] = (quad < 2) ? rv : (unsigned short)0;
    }
    f32x4 o = __builtin_amdgcn_mfma_f32_16x16x32_bf16(
        av.v, bp.v, (f32x4){0.f, 0.f, 0.f, 0.f}, 0, 0, 0);
    unsigned lo = (unsigned)f2bf_bits(o[0]) | ((unsigned)f2bf_bits(o[1]) << 16);
    unsigned hi = (unsigned)f2bf_bits(o[2]) | ((unsigned)f2bf_bits(o[3]) << 16);
    uint2 st; st.x = lo; st.y = hi;
    *(uint2*)(dst + lidx * 64 + n4 * 16 + quad * 4) = st;
  }
}

// ---------- LayerNorm: bf16 in -> fp32 out, in-kernel reduction ----------
// (r7 version, measured in the best 626.6us config)
__global__ __launch_bounds__(256) void k_ln_bf16(const unsigned short* __restrict__ ob,
                                                 const float* __restrict__ gamma,
                                                 const float* __restrict__ beta,
                                                 float* __restrict__ out){
  __shared__ float red[8];
  int tid = threadIdx.x;
  int row = blockIdx.x;
  ushort4 u = ((const ushort4*)(ob + (size_t)row * 1024))[tid];
  float x0 = bf2f(u.x), x1 = bf2f(u.y), x2 = bf2f(u.z), x3 = bf2f(u.w);
  float s  = x0 + x1 + x2 + x3;
  float ss = x0 * x0 + x1 * x1 + x2 * x2 + x3 * x3;
  #pragma unroll
  for (int off = 32; off > 0; off >>= 1){
    s  += __shfl_down(s, off);
    ss += __shfl_down(ss, off);
  }
  if ((tid & 63) == 0){ red[tid >> 6] = s; red[4 + (tid >> 6)] = ss; }
  __syncthreads();
  float S  = red[0] + red[1] + red[2] + red[3];
  float SS = red[4] + red[5] + red[6] + red[7];
  float mean = S * (1.0f / 1024.0f);
  float var  = SS * (1.0f / 1024.0f) - mean * mean;
  float rstd = rsqrtf(var + 1e-5f);
  float4 g = ((const float4*)gamma)[tid];
  float4 b = ((const float4*)beta)[tid];
  float4 v;
  v.x = (x0 - mean) * rstd * g.x + b.x;
  v.y = (x1 - mean) * rstd * g.y + b.y;
  v.z = (x2 - mean) * rstd * g.z + b.z;
  v.w = (x3 - mean) * rstd * g.w + b.w;
  ((float4*)(out + (size_t)row * 1024))[tid] = v;
}

extern "C" void kernel_launch(void* const* d_in, const int* in_sizes, int n_in,
                              void* d_out, int out_size, void* d_ws, size_t ws_size,
                              hipStream_t stream){
  const float* x     = (const float*)d_in[0];
  const float* Wq    = (const float*)d_in[1];
  const float* bq    = (const float*)d_in[2];
  const float* Wk    = (const float*)d_in[3];
  const float* bk    = (const float*)d_in[4];
  const float* Wv    = (const float*)d_in[5];
  const float* bv    = (const float*)d_in[6];
  const float* Wo    = (const float*)d_in[7];
  const float* bo    = (const float*)d_in[8];
  const float* gamma = (const float*)d_in[9];
  const float* beta  = (const float*)d_in[10];
  float* out = (float*)d_out;

  // workspace layout (bytes):
  //   [0, 6291456)            Wqkv^T bf16 (3072 x 1024)
  //   [6291456, 8388608)      Wo^T bf16  (1024 x 1024)
  //   [8388608, 75497472)     xb bf16 (32768 x 1024); reused as attn-out after GEMM1
  //   [75497472, 276824064)   qkv bf16 (32768 x 3072); reused as GEMM2 bf16 out
  char* ws = (char*)d_ws;
  unsigned short* Wqkv_t = (unsigned short*)ws;
  unsigned short* Wo_t   = (unsigned short*)(ws + 6291456);
  unsigned short* xb     = (unsigned short*)(ws + 8388608);
  unsigned short* qkv    = (unsigned short*)(ws + 75497472);
  unsigned short* aout   = xb;    // xb consumed by GEMM1 before attention writes
  unsigned short* obf    = qkv;   // qkv dead after attention; GEMM2 bf16 out

  // 1) x -> bf16
  k_convert_bf16<<<32768, 256, 0, stream>>>(x, xb, (MM * FFD) / 4);

  // 2) weight transposes (fp32 KxN -> bf16 NxK), one launch
  k_transpose4<<<dim3(32, 32, 4), 256, 0, stream>>>(Wq, Wk, Wv, Wo, Wqkv_t, Wo_t);

  // 3) QKV GEMM: (32768 x 1024) @ (1024 x 3072) -> bf16  (grid 12x128 = 1536 blocks)
  k_gemm_bt<<<dim3(NQKV / 256, MM / 256), 512, 0, stream>>>(
      xb, Wqkv_t, bq, bk, bv, qkv, MM, NQKV, FFD);

  // 4) per-position head attention (LDS-free MFMA)
  k_attention<<<MM / 4, 256, 0, stream>>>(qkv, aout);

  // 5) output GEMM: (32768 x 1024) @ (1024 x 1024) + bo -> bf16 (grid 4x128 = 512)
  k_gemm_bt<<<dim3(FFD / 256, MM / 256), 512, 0, stream>>>(
      aout, Wo_t, bo, bo, bo, obf, MM, FFD, FFD);

  // 6) LayerNorm: bf16 -> fp32 d_out
  k_ln_bf16<<<MM, 256, 0, stream>>>(obf, gamma, beta, out);
}